// Round 19
// baseline (1083.946 us; speedup 1.0000x reference)
//
#include <hip/hip_runtime.h>
#include <string.h>

// TopographicIntentMap R19: BARRIER-FREE wave-independent simulation.
// R16/R17/R18 falsified every throughput lever (chain, cvt, entry count):
// wall has ~40% synchronized idle = the per-tick barrier convoy of 16 waves
// in the 1 resident block/CU. Fix: wave = independent unit owning 4 batches x
// all 144 neurons (lane = group(16) x batch(4)). Private per-wave acc dbuf
// (144x4 f32 x2 = 4.6KB) -> all LDS deps are SAME-WAVE: program order +
// lgkmcnt replace __syncthreads. ZERO barriers in the kernel; waves drift and
// hide each other's latency.
//  - rows nnz-sorted; slot r = ranks[16r..16r+16) -> 16 groups run equal-kp
//    rows in lockstep (pad to slot max x4, ~+8%).
//  - stream [slot][k][group]: wave-load = one contiguous 128B segment
//    (R13 FETCH-blowup avoided); total ~21KB = L1-resident (R17 lesson).
//  - per-slot base + immediate offsets, 8 entries in flight, zero-mov loop.
//  - gathers ds_read_b32: quad = 4 consecutive words; cross-quad random rows
//    ~2-way avg (free, m136).
// Numerics: identical exact-f64 pipeline (absmax 0, R3-R18): per-row
// k-ascending sums, trailing +0.0 pads, LIF verbatim.

#define NN 144
#define NE 115
#define SLOTS 9
#define THREADS 1024     // 16 waves x (16 groups x 4 batches)

#define STREAM_BASE 4096
// meta ints: [0..8]=kp[r]; [16+t]=rowtab (t=r*16+g); [160+r]=slotOff bytes

__device__ __forceinline__ float u2f(unsigned u) {
    float f; memcpy(&f, &u, 4); return f;
}

__global__ void prep_kernel(const float* __restrict__ W_rec,
                            int* __restrict__ meta, char* __restrict__ wsB) {
    __shared__ int cnt[NN], sorted[NN], sOff[SLOTS], kpS[SLOTS];
    const int t = threadIdx.x;

    // zero stream region + overrun tail (max 9*32*128 = 36864, zero 40KB)
    for (int i = t; i < 40960 / 4; i += 256) ((int*)(wsB + STREAM_BASE))[i] = 0;

    if (t < NN) {
        int c = 0;
        for (int j = 0; j < NN; ++j) c += (W_rec[t * NN + j] != 0.0f);
        cnt[t] = c;
    }
    __syncthreads();
    if (t < NN) {   // deterministic descending rank (ties by index)
        int ct = cnt[t], r = 0;
        for (int j = 0; j < NN; ++j) {
            int cj = cnt[j];
            r += (cj > ct) || (cj == ct && j < t);
        }
        sorted[r] = t;
    }
    __syncthreads();
    if (t == 0) {
        int off = 0;
        for (int r = 0; r < SLOTS; ++r) {
            int mx = cnt[sorted[16 * r]];            // desc: first = slot max
            int kp = ((mx < 1 ? 1 : mx) + 3) & ~3;   // pad x4, min 4
            kpS[r] = kp; sOff[r] = off;
            meta[r] = kp; meta[160 + r] = off;
            off += kp * 128;                          // kp steps x 16 groups x 8B
        }
    }
    __syncthreads();
    if (t < NN) {
        int r = t >> 4, g = t & 15;
        int row = sorted[t];
        meta[16 + t] = row;                           // rowtab[r*16+g]
        char* base = wsB + STREAM_BASE + sOff[r] + g * 8;
        int k = 0;
        for (int j = 0; j < NN; ++j) {
            float w = W_rec[row * NN + j];
            if (w != 0.0f) {
                *(unsigned*)(base + (size_t)k * 128)    = (unsigned)j * 16u;
                *(float*)(base + (size_t)k * 128 + 4)   = w;
                ++k;
            }
        }
        // trailing pads already zeroed: +0.0*acc[0] exact no-ops
    }
}

// one entry in uint2 S = {colByte(=col*16), f32 w}; k-ascending f64 FMA.
#define GF(S)                                                           \
    {                                                                   \
        float a = *(const float*)(ldsB + ((S).x + lro));                \
        rec += (double)u2f((S).y) * (double)a;                          \
    }

__global__ __launch_bounds__(THREADS) void snn_kernel(
        const int*   __restrict__ actions,
        const float* __restrict__ spk,      // [B,8,115]
        const float* __restrict__ W_inh,    // [144,115]
        const int*   __restrict__ meta,
        const char*  __restrict__ wsB,
        const int*   __restrict__ nt_ptr,
        float*       __restrict__ out,      // [B,115]
        int B) {
    // [buf][wave][row*4 + b]: 2 x 16 x 576 floats = 73728 B; per-wave private.
    __shared__ float accF[2][16][NN * 4];

    const char* ldsB = (const char*)accF;
    const char* wsS  = wsB + STREAM_BASE;

    const int t    = threadIdx.x;
    const int lane = t & 63;
    const int wid  = t >> 6;
    const int g    = lane >> 2;             // group 0..15 (row set)
    const int b4   = lane & 3;              // batch within wave
    const int b0   = blockIdx.x * 64;
    const int bmine = b0 + wid * 4 + b4;
    const int ticks = *nt_ptr;

    // wave-uniform slot metadata (scalarized loads)
    int kp[SLOTS], sOffv[SLOTS], rows[SLOTS];
    #pragma unroll
    for (int r = 0; r < SLOTS; ++r) {
        kp[r]    = __builtin_amdgcn_readfirstlane(meta[r]);
        sOffv[r] = __builtin_amdgcn_readfirstlane(meta[160 + r]);
        rows[r]  = meta[16 + r * 16 + g];   // per-lane (quad-uniform)
    }

    // stage this wave's neighbor sums into its buffer-1 region (pre-tick0):
    // nbW[e*4+b] ; consumed by drives below, clobbered by tick0 writes later.
    float* nbW = &accF[1][wid][0];
    for (int id = lane; id < NE * 4; id += 64) {
        int e = id >> 2, bb = id & 3;
        int bi = b0 + wid * 4 + bb;
        float s = 0.0f;
        if (bi < B) {
            const float* sp = spk + ((size_t)bi * 8) * NE + e;
            #pragma unroll
            for (int n = 0; n < 8; ++n) s += sp[n * NE];
        }
        nbW[id] = s;
    }
    // zero this wave's buffer-0 region (tick-0 read buffer)
    for (int id = lane; id < NN * 4; id += 64) accF[0][wid][id] = 0.0f;
    // same-wave LDS: program order + lgkmcnt give visibility; NO barrier.

    // per-(row,batch) drives (fp64, e ascending — same association as R4-R18)
    double drv[SLOTS];
    {
        int bi = (bmine < B) ? bmine : (B - 1);
        int a = actions[bi];
        int cs = ((a == 0) ? 5 : (a == 1) ? 1 : (a == 2) ? 3 : (a == 3) ? 7 : 4) * 16;
        #pragma unroll
        for (int r = 0; r < SLOTS; ++r) {
            const int o = rows[r];
            double inh = 0.0;
            for (int e = 0; e < NE; ++e)
                inh += (double)nbW[e * 4 + b4] * (double)W_inh[o * NE + e];
            double ic = (o >= cs && o < cs + 16) ? 5.0 : 0.0;
            drv[r] = 0.5 * ic - 0.5 * inh;
        }
    }

    double v[SLOTS];
    float  accv[SLOTS];
    #pragma unroll
    for (int r = 0; r < SLOTS; ++r) { v[r] = 0.0; accv[r] = 0.0f; }

    const unsigned waveB = (unsigned)(wid * (NN * 4 * 4));  // wave region bytes

    for (int tk = 0; tk < ticks; ++tk) {
        // read buffer = tk&1 (tick0 reads zeros in buf0); write = other.
        const unsigned lro = ((tk & 1) ? 36864u : 0u) + waveB + ((unsigned)b4 << 2);
        char* WbB = (char*)ldsB + (((tk & 1) ^ 1) ? 36864u : 0u) + waveB;

        #pragma unroll
        for (int r = 0; r < SLOTS; ++r) {
            const char* p = wsS + sOffv[r] + (g << 3);   // per-lane, 128B/step
            uint2 S0 = *(const uint2*)(p);
            uint2 S1 = *(const uint2*)(p + 128);
            uint2 S2 = *(const uint2*)(p + 256);
            uint2 S3 = *(const uint2*)(p + 384);
            uint2 T0 = *(const uint2*)(p + 512);
            uint2 T1 = *(const uint2*)(p + 640);
            uint2 T2 = *(const uint2*)(p + 768);
            uint2 T3 = *(const uint2*)(p + 896);
            double rec = 0.0;
            int k = 0;
            const int kend = kp[r];
            while (k + 8 <= kend) {          // 8 entries/iter, zero-mov
                GF(S0); GF(S1); GF(S2); GF(S3);
                S0 = *(const uint2*)(p + 1024);
                S1 = *(const uint2*)(p + 1152);
                S2 = *(const uint2*)(p + 1280);
                S3 = *(const uint2*)(p + 1408);
                GF(T0); GF(T1); GF(T2); GF(T3);
                T0 = *(const uint2*)(p + 1536);
                T1 = *(const uint2*)(p + 1664);
                T2 = *(const uint2*)(p + 1792);
                T3 = *(const uint2*)(p + 1920);
                p += 1024; k += 8;
            }
            if (k < kend) { GF(S0); GF(S1); GF(S2); GF(S3); }  // kend%8==4

            const int o = rows[r];
            double x = drv[r] + 0.3 * ((o < NE) ? rec : -rec);
            double vv = v[r];
            vv += (x - vv) * 0.5;
            double sd = (vv >= 1.0) ? 1.0 : 0.0;
            vv *= (1.0 - sd);
            v[r] = vv;
            accv[r] += (float)sd;
            *(float*)(WbB + (unsigned)o * 16u + ((unsigned)b4 << 2)) = accv[r];
        }
        // no barrier: next tick's reads are this wave's own writes (lgkmcnt).
    }

    if (bmine < B) {
        #pragma unroll
        for (int r = 0; r < SLOTS; ++r) {
            int o = rows[r];
            if (o < NE) out[(size_t)bmine * NE + o] = accv[r];
        }
    }
}

extern "C" void kernel_launch(void* const* d_in, const int* in_sizes, int n_in,
                              void* d_out, int out_size, void* d_ws, size_t ws_size,
                              hipStream_t stream) {
    const int*   actions = (const int*)  d_in[0];
    const float* spk     = (const float*)d_in[1];
    const float* W_rec   = (const float*)d_in[2];
    const float* W_inh   = (const float*)d_in[3];
    const int*   nt      = (const int*)  d_in[4];
    float* out = (float*)d_out;
    int B = in_sizes[0];

    int*  meta = (int*)d_ws;
    char* wsB  = (char*)d_ws;

    prep_kernel<<<1, 256, 0, stream>>>(W_rec, meta, wsB);
    int nblocks = (B + 63) / 64;
    snn_kernel<<<nblocks, THREADS, 0, stream>>>(actions, spk, W_inh, meta, wsB,
                                                nt, out, B);
}

// Round 20
// 799.960 us; speedup vs baseline: 1.3550x; 1.3550x over previous
//
#include <hip/hip_runtime.h>
#include <string.h>

// TopographicIntentMap R20: barrier-free wave-independent sim, R19 bugs fixed.
// R19 post-mortem: concept passed (absmax 0) but SPILLED (WRITE 294MB, rule
// #20: loop-indexed state arrays -> scratch) and bank-conflicted (46M: 16B row
// stride = 8 bank-quads). Fixes:
//  (1) per-slot state in NAMED registers via macros (d0..d8/v0..v8/a0..a8),
//      every index compile-time -> no scratch. Tripwire: WRITE ~7.4MB.
//  (2) acc row stride 20B (col*20, gcd(5,32)=1): random cols spread across
//      all 32 banks; quad's 4 consecutive words ~2-way = free (m136).
//  (3) 4-deep stream pipeline; loop never loads past the slot (no overrun).
// Kept from R19: ZERO barriers (wave owns 4 batches x 144 neurons; acc dbuf
// private per wave -> same-wave program order + lgkmcnt replace syncthreads);
// nnz-sorted slots (16 equal-rank rows/slot, pad to slot max x4);
// [slot][k][group] stream = one 128B line per wave-load, ~21KB L1-resident.
// Numerics: exact-f64 pipeline of R3-R19 (absmax 0 all rounds); per-row
// k-ascending sums; trailing +0.0 pads; LIF verbatim.

#define NN 144
#define NE 115
#define SLOTS 9
#define THREADS 1024     // 16 waves x (16 groups x 4 batches)

#define STREAM_BASE 4096
#define ROWB 20u         // acc row stride bytes (5 words)
#define WAVEB (NN * ROWB)            // 2880 B per wave per buffer
#define BUFB  (16 * WAVEB)           // 46080 B per buffer

__device__ __forceinline__ float u2f(unsigned u) {
    float f; memcpy(&f, &u, 4); return f;
}

__global__ void prep_kernel(const float* __restrict__ W_rec,
                            int* __restrict__ meta, char* __restrict__ wsB) {
    __shared__ int cnt[NN], sorted[NN], sOff[SLOTS];
    const int t = threadIdx.x;

    // zero stream region (pads): 32KB covers max 9*32*128
    for (int i = t; i < 32768 / 4; i += 256) ((int*)(wsB + STREAM_BASE))[i] = 0;

    if (t < NN) {
        int c = 0;
        for (int j = 0; j < NN; ++j) c += (W_rec[t * NN + j] != 0.0f);
        cnt[t] = c;
    }
    __syncthreads();
    if (t < NN) {   // deterministic descending rank (ties by index)
        int ct = cnt[t], r = 0;
        for (int j = 0; j < NN; ++j) {
            int cj = cnt[j];
            r += (cj > ct) || (cj == ct && j < t);
        }
        sorted[r] = t;
    }
    __syncthreads();
    if (t == 0) {
        int off = 0;
        for (int r = 0; r < SLOTS; ++r) {
            int mx = cnt[sorted[16 * r]];            // desc: first = slot max
            int kp = ((mx < 1 ? 1 : mx) + 3) & ~3;   // pad x4, min 4
            sOff[r] = off;
            meta[r] = kp; meta[160 + r] = off;
            off += kp * 128;                          // kp steps x 16 groups x 8B
        }
    }
    __syncthreads();
    if (t < NN) {
        int r = t >> 4, g = t & 15;
        int row = sorted[t];
        meta[16 + t] = row;                           // rowtab[r*16+g]
        char* base = wsB + STREAM_BASE + sOff[r] + g * 8;
        int k = 0;
        for (int j = 0; j < NN; ++j) {
            float w = W_rec[row * NN + j];
            if (w != 0.0f) {
                *(unsigned*)(base + (size_t)k * 128)    = (unsigned)j * ROWB;
                *(float*)(base + (size_t)k * 128 + 4)   = w;
                ++k;
            }
        }
        // trailing pads already zeroed: +0.0*acc[0] exact no-ops
    }
}

__global__ __launch_bounds__(THREADS) void snn_kernel(
        const int*   __restrict__ actions,
        const float* __restrict__ spk,      // [B,8,115]
        const float* __restrict__ W_inh,    // [144,115]
        const int*   __restrict__ meta,
        const char*  __restrict__ wsB,
        const int*   __restrict__ nt_ptr,
        float*       __restrict__ out,      // [B,115]
        int B) {
    __shared__ __align__(16) char accB[2 * BUFB];   // 92160 B, per-wave private

    const char* wsS = wsB + STREAM_BASE;

    const int t    = threadIdx.x;
    const int lane = t & 63;
    const int wid  = t >> 6;
    const int g    = lane >> 2;             // group 0..15 (row within slot)
    const int b4   = lane & 3;              // batch within wave
    const int b0   = blockIdx.x * 64;
    const int bmine = b0 + wid * 4 + b4;
    const int ticks = *nt_ptr;
    const unsigned waveOff = (unsigned)wid * WAVEB;

    // wave-uniform slot metadata (SGPR) — named, compile-time indexed
    const int KP0 = __builtin_amdgcn_readfirstlane(meta[0]);
    const int KP1 = __builtin_amdgcn_readfirstlane(meta[1]);
    const int KP2 = __builtin_amdgcn_readfirstlane(meta[2]);
    const int KP3 = __builtin_amdgcn_readfirstlane(meta[3]);
    const int KP4 = __builtin_amdgcn_readfirstlane(meta[4]);
    const int KP5 = __builtin_amdgcn_readfirstlane(meta[5]);
    const int KP6 = __builtin_amdgcn_readfirstlane(meta[6]);
    const int KP7 = __builtin_amdgcn_readfirstlane(meta[7]);
    const int KP8 = __builtin_amdgcn_readfirstlane(meta[8]);
    const int SO0 = __builtin_amdgcn_readfirstlane(meta[160]);
    const int SO1 = __builtin_amdgcn_readfirstlane(meta[161]);
    const int SO2 = __builtin_amdgcn_readfirstlane(meta[162]);
    const int SO3 = __builtin_amdgcn_readfirstlane(meta[163]);
    const int SO4 = __builtin_amdgcn_readfirstlane(meta[164]);
    const int SO5 = __builtin_amdgcn_readfirstlane(meta[165]);
    const int SO6 = __builtin_amdgcn_readfirstlane(meta[166]);
    const int SO7 = __builtin_amdgcn_readfirstlane(meta[167]);
    const int SO8 = __builtin_amdgcn_readfirstlane(meta[168]);
    const int R0_ = meta[16 + 0 * 16 + g];
    const int R1_ = meta[16 + 1 * 16 + g];
    const int R2_ = meta[16 + 2 * 16 + g];
    const int R3_ = meta[16 + 3 * 16 + g];
    const int R4_ = meta[16 + 4 * 16 + g];
    const int R5_ = meta[16 + 5 * 16 + g];
    const int R6_ = meta[16 + 6 * 16 + g];
    const int R7_ = meta[16 + 7 * 16 + g];
    const int R8_ = meta[16 + 8 * 16 + g];

    // stage this wave's neighbor sums into its buf1 region (pre-tick0 only;
    // tick0 reads buf0 zeros, writes buf1 AFTER drives are consumed).
    float* nbW = (float*)(accB + BUFB + waveOff);   // NE*4 floats <= 720
    for (int id = lane; id < NE * 4; id += 64) {
        int e = id >> 2, bb = id & 3;
        int bi = b0 + wid * 4 + bb;
        float s = 0.0f;
        if (bi < B) {
            const float* sp = spk + ((size_t)bi * 8) * NE + e;
            #pragma unroll
            for (int n = 0; n < 8; ++n) s += sp[n * NE];
        }
        nbW[id] = s;
    }
    // zero this wave's buf0 region (tick-0 read buffer); same-wave: no barrier
    {
        float* z = (float*)(accB + waveOff);
        for (int id = lane; id < (int)(WAVEB / 4); id += 64) z[id] = 0.0f;
    }

    // drives (fp64, e ascending — same association as R4-R19), named state
    int abi = (bmine < B) ? bmine : (B - 1);
    int act = actions[abi];
    const int cs = ((act == 0) ? 5 : (act == 1) ? 1 : (act == 2) ? 3 :
                    (act == 3) ? 7 : 4) * 16;
#define DRIVE(RR)                                                        \
    ({                                                                   \
        double inh = 0.0;                                                \
        for (int e = 0; e < NE; ++e)                                     \
            inh += (double)nbW[e * 4 + b4] * (double)W_inh[(RR) * NE + e]; \
        double ic = ((RR) >= cs && (RR) < cs + 16) ? 5.0 : 0.0;          \
        0.5 * ic - 0.5 * inh;                                            \
    })
    double d0 = DRIVE(R0_), d1 = DRIVE(R1_), d2 = DRIVE(R2_);
    double d3 = DRIVE(R3_), d4 = DRIVE(R4_), d5 = DRIVE(R5_);
    double d6 = DRIVE(R6_), d7 = DRIVE(R7_), d8 = DRIVE(R8_);

    double v0 = 0, v1 = 0, v2 = 0, v3 = 0, v4 = 0, v5 = 0, v6 = 0, v7 = 0, v8 = 0;
    float  a0 = 0, a1 = 0, a2 = 0, a3 = 0, a4 = 0, a5 = 0, a6 = 0, a7 = 0, a8 = 0;

    const unsigned gOff = (unsigned)(g << 3);
    const unsigned b4B  = (unsigned)(b4 << 2);

// one slot: 4-deep pipeline, 4 entries/iter, never loads past the slot.
#define SLOT(SO, KP, RR, DD, VV, AA)                                     \
    {                                                                    \
        const char* p = wsS + (SO) + gOff;                               \
        uint2 S0 = *(const uint2*)(p);                                   \
        uint2 S1 = *(const uint2*)(p + 128);                             \
        uint2 S2 = *(const uint2*)(p + 256);                             \
        uint2 S3 = *(const uint2*)(p + 384);                             \
        double rec = 0.0;                                                \
        int k = 0;                                                       \
        while (k + 8 <= (KP)) {                                          \
            float x0 = *(const float*)(rdB + (S0.x + b4B));              \
            float x1 = *(const float*)(rdB + (S1.x + b4B));              \
            float x2 = *(const float*)(rdB + (S2.x + b4B));              \
            float x3 = *(const float*)(rdB + (S3.x + b4B));              \
            rec += (double)u2f(S0.y) * (double)x0;                       \
            rec += (double)u2f(S1.y) * (double)x1;                       \
            rec += (double)u2f(S2.y) * (double)x2;                       \
            rec += (double)u2f(S3.y) * (double)x3;                       \
            S0 = *(const uint2*)(p + 512);                               \
            S1 = *(const uint2*)(p + 640);                               \
            S2 = *(const uint2*)(p + 768);                               \
            S3 = *(const uint2*)(p + 896);                               \
            p += 512; k += 4;                                            \
        }                                                                \
        {   /* final 4 entries already in S0..S3 */                      \
            float x0 = *(const float*)(rdB + (S0.x + b4B));              \
            float x1 = *(const float*)(rdB + (S1.x + b4B));              \
            float x2 = *(const float*)(rdB + (S2.x + b4B));              \
            float x3 = *(const float*)(rdB + (S3.x + b4B));              \
            rec += (double)u2f(S0.y) * (double)x0;                       \
            rec += (double)u2f(S1.y) * (double)x1;                       \
            rec += (double)u2f(S2.y) * (double)x2;                       \
            rec += (double)u2f(S3.y) * (double)x3;                       \
        }                                                                \
        double x = (DD) + 0.3 * (((RR) < NE) ? rec : -rec);              \
        double vv = (VV);                                                \
        vv += (x - vv) * 0.5;                                            \
        double sd = (vv >= 1.0) ? 1.0 : 0.0;                             \
        vv *= (1.0 - sd);                                                \
        (VV) = vv;                                                       \
        (AA) += (float)sd;                                               \
        *(float*)(wrB + (unsigned)(RR) * ROWB + b4B) = (AA);             \
    }

    for (int tk = 0; tk < ticks; ++tk) {
        // read buf = tk&1 (tick0 reads zeroed buf0); write = the other.
        const char* rdB = accB + ((tk & 1) ? BUFB : 0u) + waveOff;
        char*       wrB = accB + ((tk & 1) ? 0u : BUFB) + waveOff;
        SLOT(SO0, KP0, R0_, d0, v0, a0);
        SLOT(SO1, KP1, R1_, d1, v1, a1);
        SLOT(SO2, KP2, R2_, d2, v2, a2);
        SLOT(SO3, KP3, R3_, d3, v3, a3);
        SLOT(SO4, KP4, R4_, d4, v4, a4);
        SLOT(SO5, KP5, R5_, d5, v5, a5);
        SLOT(SO6, KP6, R6_, d6, v6, a6);
        SLOT(SO7, KP7, R7_, d7, v7, a7);
        SLOT(SO8, KP8, R8_, d8, v8, a8);
        // no barrier: next tick reads THIS wave's own writes (program order).
    }

    if (bmine < B) {
        float* ob = out + (size_t)bmine * NE;
        if (R0_ < NE) ob[R0_] = a0;
        if (R1_ < NE) ob[R1_] = a1;
        if (R2_ < NE) ob[R2_] = a2;
        if (R3_ < NE) ob[R3_] = a3;
        if (R4_ < NE) ob[R4_] = a4;
        if (R5_ < NE) ob[R5_] = a5;
        if (R6_ < NE) ob[R6_] = a6;
        if (R7_ < NE) ob[R7_] = a7;
        if (R8_ < NE) ob[R8_] = a8;
    }
}

extern "C" void kernel_launch(void* const* d_in, const int* in_sizes, int n_in,
                              void* d_out, int out_size, void* d_ws, size_t ws_size,
                              hipStream_t stream) {
    const int*   actions = (const int*)  d_in[0];
    const float* spk     = (const float*)d_in[1];
    const float* W_rec   = (const float*)d_in[2];
    const float* W_inh   = (const float*)d_in[3];
    const int*   nt      = (const int*)  d_in[4];
    float* out = (float*)d_out;
    int B = in_sizes[0];

    int*  meta = (int*)d_ws;
    char* wsB  = (char*)d_ws;

    prep_kernel<<<1, 256, 0, stream>>>(W_rec, meta, wsB);
    int nblocks = (B + 63) / 64;
    snn_kernel<<<nblocks, THREADS, 0, stream>>>(actions, spk, W_inh, meta, wsB,
                                                nt, out, B);
}

// Round 21
// 799.359 us; speedup vs baseline: 1.3560x; 1.0008x over previous
//
#include <hip/hip_runtime.h>
#include <string.h>

// TopographicIntentMap R21: barrier-free wave-independent sim = R20 + the one
// missing flag. R20 post-mortem: VGPR_Count=64 (backend's default occupancy
// target with bare __launch_bounds__(1024)) forced spills (WRITE 74MB, FETCH
// 1GB of scratch traffic). Fix: __launch_bounds__(1024, 4) -> 4 waves/EU min
// -> 128 VGPR budget -> the ~85-reg named state (9 f64 v + 9 f64 drv + 9 f32
// acc + 4-deep stream pipeline) stays in registers.
// Kept from R19/R20 (both passed, absmax 0): ZERO barriers — wave owns 4
// batches x 144 neurons; acc dbuf private per wave so same-wave program order
// + lgkmcnt replace __syncthreads; waves drift -> DS and VALU phases of
// different waves overlap (R15's barrier phase-aligns them: VALU 17.5K + DS
// 14K ~= wall 28.3K cyc/tick, pipes alternating).
// nnz-sorted slots (16 equal-rank rows/slot, pad x4), [slot][k][group] stream
// (one 128B line per wave-load, ~20KB shared by all 16 waves -> L1-resident),
// acc row stride 20B (gcd(5,32)=1 bank spread).
// Numerics: exact-f64 pipeline of R3-R20 (absmax 0 all rounds); per-row
// k-ascending sums; trailing +0.0 pads; LIF verbatim.

#define NN 144
#define NE 115
#define SLOTS 9
#define THREADS 1024     // 16 waves x (16 groups x 4 batches)

#define STREAM_BASE 4096
#define ROWB 20u         // acc row stride bytes (5 words)
#define WAVEB (NN * ROWB)            // 2880 B per wave per buffer
#define BUFB  (16 * WAVEB)           // 46080 B per buffer

__device__ __forceinline__ float u2f(unsigned u) {
    float f; memcpy(&f, &u, 4); return f;
}

__global__ void prep_kernel(const float* __restrict__ W_rec,
                            int* __restrict__ meta, char* __restrict__ wsB) {
    __shared__ int cnt[NN], sorted[NN], sOff[SLOTS];
    const int t = threadIdx.x;

    // zero stream region (pads): 32KB covers max 9*40*128
    for (int i = t; i < 32768 / 4; i += 256) ((int*)(wsB + STREAM_BASE))[i] = 0;

    if (t < NN) {
        int c = 0;
        for (int j = 0; j < NN; ++j) c += (W_rec[t * NN + j] != 0.0f);
        cnt[t] = c;
    }
    __syncthreads();
    if (t < NN) {   // deterministic descending rank (ties by index)
        int ct = cnt[t], r = 0;
        for (int j = 0; j < NN; ++j) {
            int cj = cnt[j];
            r += (cj > ct) || (cj == ct && j < t);
        }
        sorted[r] = t;
    }
    __syncthreads();
    if (t == 0) {
        int off = 0;
        for (int r = 0; r < SLOTS; ++r) {
            int mx = cnt[sorted[16 * r]];            // desc: first = slot max
            int kp = ((mx < 1 ? 1 : mx) + 3) & ~3;   // pad x4, min 4
            sOff[r] = off;
            meta[r] = kp; meta[160 + r] = off;
            off += kp * 128;                          // kp steps x 16 groups x 8B
        }
    }
    __syncthreads();
    if (t < NN) {
        int r = t >> 4, g = t & 15;
        int row = sorted[t];
        meta[16 + t] = row;                           // rowtab[r*16+g]
        char* base = wsB + STREAM_BASE + sOff[r] + g * 8;
        int k = 0;
        for (int j = 0; j < NN; ++j) {
            float w = W_rec[row * NN + j];
            if (w != 0.0f) {
                *(unsigned*)(base + (size_t)k * 128)    = (unsigned)j * ROWB;
                *(float*)(base + (size_t)k * 128 + 4)   = w;
                ++k;
            }
        }
        // trailing pads already zeroed: +0.0*acc[0] exact no-ops
    }
}

__global__ __launch_bounds__(THREADS, 4) void snn_kernel(
        const int*   __restrict__ actions,
        const float* __restrict__ spk,      // [B,8,115]
        const float* __restrict__ W_inh,    // [144,115]
        const int*   __restrict__ meta,
        const char*  __restrict__ wsB,
        const int*   __restrict__ nt_ptr,
        float*       __restrict__ out,      // [B,115]
        int B) {
    __shared__ __align__(16) char accB[2 * BUFB];   // 92160 B, per-wave private

    const char* wsS = wsB + STREAM_BASE;

    const int t    = threadIdx.x;
    const int lane = t & 63;
    const int wid  = t >> 6;
    const int g    = lane >> 2;             // group 0..15 (row within slot)
    const int b4   = lane & 3;              // batch within wave
    const int b0   = blockIdx.x * 64;
    const int bmine = b0 + wid * 4 + b4;
    const int ticks = *nt_ptr;
    const unsigned waveOff = (unsigned)wid * WAVEB;

    // wave-uniform slot metadata (SGPR) — named, compile-time indexed
    const int KP0 = __builtin_amdgcn_readfirstlane(meta[0]);
    const int KP1 = __builtin_amdgcn_readfirstlane(meta[1]);
    const int KP2 = __builtin_amdgcn_readfirstlane(meta[2]);
    const int KP3 = __builtin_amdgcn_readfirstlane(meta[3]);
    const int KP4 = __builtin_amdgcn_readfirstlane(meta[4]);
    const int KP5 = __builtin_amdgcn_readfirstlane(meta[5]);
    const int KP6 = __builtin_amdgcn_readfirstlane(meta[6]);
    const int KP7 = __builtin_amdgcn_readfirstlane(meta[7]);
    const int KP8 = __builtin_amdgcn_readfirstlane(meta[8]);
    const int SO0 = __builtin_amdgcn_readfirstlane(meta[160]);
    const int SO1 = __builtin_amdgcn_readfirstlane(meta[161]);
    const int SO2 = __builtin_amdgcn_readfirstlane(meta[162]);
    const int SO3 = __builtin_amdgcn_readfirstlane(meta[163]);
    const int SO4 = __builtin_amdgcn_readfirstlane(meta[164]);
    const int SO5 = __builtin_amdgcn_readfirstlane(meta[165]);
    const int SO6 = __builtin_amdgcn_readfirstlane(meta[166]);
    const int SO7 = __builtin_amdgcn_readfirstlane(meta[167]);
    const int SO8 = __builtin_amdgcn_readfirstlane(meta[168]);
    const int R0_ = meta[16 + 0 * 16 + g];
    const int R1_ = meta[16 + 1 * 16 + g];
    const int R2_ = meta[16 + 2 * 16 + g];
    const int R3_ = meta[16 + 3 * 16 + g];
    const int R4_ = meta[16 + 4 * 16 + g];
    const int R5_ = meta[16 + 5 * 16 + g];
    const int R6_ = meta[16 + 6 * 16 + g];
    const int R7_ = meta[16 + 7 * 16 + g];
    const int R8_ = meta[16 + 8 * 16 + g];

    // stage this wave's neighbor sums into its buf1 region (pre-tick0 only;
    // tick0 reads buf0 zeros, writes buf1 AFTER drives are consumed).
    float* nbW = (float*)(accB + BUFB + waveOff);   // NE*4 floats <= 720
    for (int id = lane; id < NE * 4; id += 64) {
        int e = id >> 2, bb = id & 3;
        int bi = b0 + wid * 4 + bb;
        float s = 0.0f;
        if (bi < B) {
            const float* sp = spk + ((size_t)bi * 8) * NE + e;
            #pragma unroll
            for (int n = 0; n < 8; ++n) s += sp[n * NE];
        }
        nbW[id] = s;
    }
    // zero this wave's buf0 region (tick-0 read buffer); same-wave: no barrier
    {
        float* z = (float*)(accB + waveOff);
        for (int id = lane; id < (int)(WAVEB / 4); id += 64) z[id] = 0.0f;
    }

    // drives (fp64, e ascending — same association as R4-R20), named state
    int abi = (bmine < B) ? bmine : (B - 1);
    int act = actions[abi];
    const int cs = ((act == 0) ? 5 : (act == 1) ? 1 : (act == 2) ? 3 :
                    (act == 3) ? 7 : 4) * 16;
#define DRIVE(RR)                                                        \
    ({                                                                   \
        double inh = 0.0;                                                \
        for (int e = 0; e < NE; ++e)                                     \
            inh += (double)nbW[e * 4 + b4] * (double)W_inh[(RR) * NE + e]; \
        double ic = ((RR) >= cs && (RR) < cs + 16) ? 5.0 : 0.0;          \
        0.5 * ic - 0.5 * inh;                                            \
    })
    double d0 = DRIVE(R0_), d1 = DRIVE(R1_), d2 = DRIVE(R2_);
    double d3 = DRIVE(R3_), d4 = DRIVE(R4_), d5 = DRIVE(R5_);
    double d6 = DRIVE(R6_), d7 = DRIVE(R7_), d8 = DRIVE(R8_);

    double v0 = 0, v1 = 0, v2 = 0, v3 = 0, v4 = 0, v5 = 0, v6 = 0, v7 = 0, v8 = 0;
    float  a0 = 0, a1 = 0, a2 = 0, a3 = 0, a4 = 0, a5 = 0, a6 = 0, a7 = 0, a8 = 0;

    const unsigned gOff = (unsigned)(g << 3);
    const unsigned b4B  = (unsigned)(b4 << 2);

// one slot: 4-deep pipeline, 4 entries/iter, never loads past the slot.
#define SLOT(SO, KP, RR, DD, VV, AA)                                     \
    {                                                                    \
        const char* p = wsS + (SO) + gOff;                               \
        uint2 S0 = *(const uint2*)(p);                                   \
        uint2 S1 = *(const uint2*)(p + 128);                             \
        uint2 S2 = *(const uint2*)(p + 256);                             \
        uint2 S3 = *(const uint2*)(p + 384);                             \
        double rec = 0.0;                                                \
        int k = 0;                                                       \
        while (k + 8 <= (KP)) {                                          \
            float x0 = *(const float*)(rdB + (S0.x + b4B));              \
            float x1 = *(const float*)(rdB + (S1.x + b4B));              \
            float x2 = *(const float*)(rdB + (S2.x + b4B));              \
            float x3 = *(const float*)(rdB + (S3.x + b4B));              \
            rec += (double)u2f(S0.y) * (double)x0;                       \
            rec += (double)u2f(S1.y) * (double)x1;                       \
            rec += (double)u2f(S2.y) * (double)x2;                       \
            rec += (double)u2f(S3.y) * (double)x3;                       \
            S0 = *(const uint2*)(p + 512);                               \
            S1 = *(const uint2*)(p + 640);                               \
            S2 = *(const uint2*)(p + 768);                               \
            S3 = *(const uint2*)(p + 896);                               \
            p += 512; k += 4;                                            \
        }                                                                \
        {   /* final 4 entries already in S0..S3 */                      \
            float x0 = *(const float*)(rdB + (S0.x + b4B));              \
            float x1 = *(const float*)(rdB + (S1.x + b4B));              \
            float x2 = *(const float*)(rdB + (S2.x + b4B));              \
            float x3 = *(const float*)(rdB + (S3.x + b4B));              \
            rec += (double)u2f(S0.y) * (double)x0;                       \
            rec += (double)u2f(S1.y) * (double)x1;                       \
            rec += (double)u2f(S2.y) * (double)x2;                       \
            rec += (double)u2f(S3.y) * (double)x3;                       \
        }                                                                \
        double x = (DD) + 0.3 * (((RR) < NE) ? rec : -rec);              \
        double vv = (VV);                                                \
        vv += (x - vv) * 0.5;                                            \
        double sd = (vv >= 1.0) ? 1.0 : 0.0;                             \
        vv *= (1.0 - sd);                                                \
        (VV) = vv;                                                       \
        (AA) += (float)sd;                                               \
        *(float*)(wrB + (unsigned)(RR) * ROWB + b4B) = (AA);             \
    }

    for (int tk = 0; tk < ticks; ++tk) {
        // read buf = tk&1 (tick0 reads zeroed buf0); write = the other.
        const char* rdB = accB + ((tk & 1) ? BUFB : 0u) + waveOff;
        char*       wrB = accB + ((tk & 1) ? 0u : BUFB) + waveOff;
        SLOT(SO0, KP0, R0_, d0, v0, a0);
        SLOT(SO1, KP1, R1_, d1, v1, a1);
        SLOT(SO2, KP2, R2_, d2, v2, a2);
        SLOT(SO3, KP3, R3_, d3, v3, a3);
        SLOT(SO4, KP4, R4_, d4, v4, a4);
        SLOT(SO5, KP5, R5_, d5, v5, a5);
        SLOT(SO6, KP6, R6_, d6, v6, a6);
        SLOT(SO7, KP7, R7_, d7, v7, a7);
        SLOT(SO8, KP8, R8_, d8, v8, a8);
        // no barrier: next tick reads THIS wave's own writes (program order).
    }

    if (bmine < B) {
        float* ob = out + (size_t)bmine * NE;
        if (R0_ < NE) ob[R0_] = a0;
        if (R1_ < NE) ob[R1_] = a1;
        if (R2_ < NE) ob[R2_] = a2;
        if (R3_ < NE) ob[R3_] = a3;
        if (R4_ < NE) ob[R4_] = a4;
        if (R5_ < NE) ob[R5_] = a5;
        if (R6_ < NE) ob[R6_] = a6;
        if (R7_ < NE) ob[R7_] = a7;
        if (R8_ < NE) ob[R8_] = a8;
    }
}

extern "C" void kernel_launch(void* const* d_in, const int* in_sizes, int n_in,
                              void* d_out, int out_size, void* d_ws, size_t ws_size,
                              hipStream_t stream) {
    const int*   actions = (const int*)  d_in[0];
    const float* spk     = (const float*)d_in[1];
    const float* W_rec   = (const float*)d_in[2];
    const float* W_inh   = (const float*)d_in[3];
    const int*   nt      = (const int*)  d_in[4];
    float* out = (float*)d_out;
    int B = in_sizes[0];

    int*  meta = (int*)d_ws;
    char* wsB  = (char*)d_ws;

    prep_kernel<<<1, 256, 0, stream>>>(W_rec, meta, wsB);
    int nblocks = (B + 63) / 64;
    snn_kernel<<<nblocks, THREADS, 0, stream>>>(actions, spk, W_inh, meta, wsB,
                                                nt, out, B);
}

// Round 22
// 547.490 us; speedup vs baseline: 1.9798x; 1.4600x over previous
//
#include <hip/hip_runtime.h>
#include <string.h>

// TopographicIntentMap R22: barrier-free wave-independent sim, 512-thr blocks.
// R19-21 all spilled at VGPR=64 with 1024-thread blocks (allocator caps at 64
// for 16-wave blocks; state needs ~75). R14 datum: 512-thread blocks compile
// to VGPR=80 naturally. Same design as R21 otherwise:
//  - ZERO barriers: wave owns 4 batches x 144 neurons; acc dbuf private per
//    wave -> same-wave program order replaces __syncthreads (absmax 0 in
//    R19/20/21 proves the dependency model).
//  - 8 waves/block, LDS 45KB -> 2-3 independent blocks/CU (16-24 drifting
//    waves/CU), grid 512.
//  - nnz-sorted slots (16 equal-rank rows/slot, pad x4), [slot][k][group]
//    stream (one 128B line per wave-load, ~20KB L1-resident), acc row stride
//    20B (gcd(5,32)=1 bank spread), named per-slot state (no dyn indexing).
// Numerics: exact-f64 pipeline of R3-R21 (absmax 0 all rounds); per-row
// k-ascending sums; trailing +0.0 pads; LIF verbatim.

#define NN 144
#define NE 115
#define SLOTS 9
#define THREADS 512      // 8 waves x (16 groups x 4 batches)

#define STREAM_BASE 4096
#define ROWB 20u         // acc row stride bytes (5 words)
#define WAVEB (NN * ROWB)            // 2880 B per wave per buffer
#define NWAVE 8
#define BUFB  (NWAVE * WAVEB)        // 23040 B per buffer

__device__ __forceinline__ float u2f(unsigned u) {
    float f; memcpy(&f, &u, 4); return f;
}

__global__ void prep_kernel(const float* __restrict__ W_rec,
                            int* __restrict__ meta, char* __restrict__ wsB) {
    __shared__ int cnt[NN], sorted[NN], sOff[SLOTS];
    const int t = threadIdx.x;

    // zero stream region (pads): 32KB covers max 9*40*128
    for (int i = t; i < 32768 / 4; i += 256) ((int*)(wsB + STREAM_BASE))[i] = 0;

    if (t < NN) {
        int c = 0;
        for (int j = 0; j < NN; ++j) c += (W_rec[t * NN + j] != 0.0f);
        cnt[t] = c;
    }
    __syncthreads();
    if (t < NN) {   // deterministic descending rank (ties by index)
        int ct = cnt[t], r = 0;
        for (int j = 0; j < NN; ++j) {
            int cj = cnt[j];
            r += (cj > ct) || (cj == ct && j < t);
        }
        sorted[r] = t;
    }
    __syncthreads();
    if (t == 0) {
        int off = 0;
        for (int r = 0; r < SLOTS; ++r) {
            int mx = cnt[sorted[16 * r]];            // desc: first = slot max
            int kp = ((mx < 1 ? 1 : mx) + 3) & ~3;   // pad x4, min 4
            sOff[r] = off;
            meta[r] = kp; meta[160 + r] = off;
            off += kp * 128;                          // kp steps x 16 groups x 8B
        }
    }
    __syncthreads();
    if (t < NN) {
        int r = t >> 4, g = t & 15;
        int row = sorted[t];
        meta[16 + t] = row;                           // rowtab[r*16+g]
        char* base = wsB + STREAM_BASE + sOff[r] + g * 8;
        int k = 0;
        for (int j = 0; j < NN; ++j) {
            float w = W_rec[row * NN + j];
            if (w != 0.0f) {
                *(unsigned*)(base + (size_t)k * 128)    = (unsigned)j * ROWB;
                *(float*)(base + (size_t)k * 128 + 4)   = w;
                ++k;
            }
        }
        // trailing pads already zeroed: +0.0*acc[0] exact no-ops
    }
}

__global__ __launch_bounds__(THREADS) void snn_kernel(
        const int*   __restrict__ actions,
        const float* __restrict__ spk,      // [B,8,115]
        const float* __restrict__ W_inh,    // [144,115]
        const int*   __restrict__ meta,
        const char*  __restrict__ wsB,
        const int*   __restrict__ nt_ptr,
        float*       __restrict__ out,      // [B,115]
        int B) {
    __shared__ __align__(16) char accB[2 * BUFB];   // 46080 B, per-wave private

    const char* wsS = wsB + STREAM_BASE;

    const int t    = threadIdx.x;
    const int lane = t & 63;
    const int wid  = t >> 6;                // 0..7
    const int g    = lane >> 2;             // group 0..15 (row within slot)
    const int b4   = lane & 3;              // batch within wave
    const int b0   = blockIdx.x * 32;
    const int bmine = b0 + wid * 4 + b4;
    const int ticks = *nt_ptr;
    const unsigned waveOff = (unsigned)wid * WAVEB;

    // wave-uniform slot metadata (SGPR) — named, compile-time indexed
    const int KP0 = __builtin_amdgcn_readfirstlane(meta[0]);
    const int KP1 = __builtin_amdgcn_readfirstlane(meta[1]);
    const int KP2 = __builtin_amdgcn_readfirstlane(meta[2]);
    const int KP3 = __builtin_amdgcn_readfirstlane(meta[3]);
    const int KP4 = __builtin_amdgcn_readfirstlane(meta[4]);
    const int KP5 = __builtin_amdgcn_readfirstlane(meta[5]);
    const int KP6 = __builtin_amdgcn_readfirstlane(meta[6]);
    const int KP7 = __builtin_amdgcn_readfirstlane(meta[7]);
    const int KP8 = __builtin_amdgcn_readfirstlane(meta[8]);
    const int SO0 = __builtin_amdgcn_readfirstlane(meta[160]);
    const int SO1 = __builtin_amdgcn_readfirstlane(meta[161]);
    const int SO2 = __builtin_amdgcn_readfirstlane(meta[162]);
    const int SO3 = __builtin_amdgcn_readfirstlane(meta[163]);
    const int SO4 = __builtin_amdgcn_readfirstlane(meta[164]);
    const int SO5 = __builtin_amdgcn_readfirstlane(meta[165]);
    const int SO6 = __builtin_amdgcn_readfirstlane(meta[166]);
    const int SO7 = __builtin_amdgcn_readfirstlane(meta[167]);
    const int SO8 = __builtin_amdgcn_readfirstlane(meta[168]);
    const int R0_ = meta[16 + 0 * 16 + g];
    const int R1_ = meta[16 + 1 * 16 + g];
    const int R2_ = meta[16 + 2 * 16 + g];
    const int R3_ = meta[16 + 3 * 16 + g];
    const int R4_ = meta[16 + 4 * 16 + g];
    const int R5_ = meta[16 + 5 * 16 + g];
    const int R6_ = meta[16 + 6 * 16 + g];
    const int R7_ = meta[16 + 7 * 16 + g];
    const int R8_ = meta[16 + 8 * 16 + g];

    // stage this wave's neighbor sums into its buf1 region (pre-tick0 only;
    // tick0 reads buf0 zeros, writes buf1 AFTER drives are consumed).
    float* nbW = (float*)(accB + BUFB + waveOff);   // NE*4 floats <= 720
    for (int id = lane; id < NE * 4; id += 64) {
        int e = id >> 2, bb = id & 3;
        int bi = b0 + wid * 4 + bb;
        float s = 0.0f;
        if (bi < B) {
            const float* sp = spk + ((size_t)bi * 8) * NE + e;
            #pragma unroll
            for (int n = 0; n < 8; ++n) s += sp[n * NE];
        }
        nbW[id] = s;
    }
    // zero this wave's buf0 region (tick-0 read buffer); same-wave: no barrier
    {
        float* z = (float*)(accB + waveOff);
        for (int id = lane; id < (int)(WAVEB / 4); id += 64) z[id] = 0.0f;
    }

    // drives (fp64, e ascending — same association as R4-R21), named state
    int abi = (bmine < B) ? bmine : (B - 1);
    int act = actions[abi];
    const int cs = ((act == 0) ? 5 : (act == 1) ? 1 : (act == 2) ? 3 :
                    (act == 3) ? 7 : 4) * 16;
#define DRIVE(RR)                                                        \
    ({                                                                   \
        double inh = 0.0;                                                \
        for (int e = 0; e < NE; ++e)                                     \
            inh += (double)nbW[e * 4 + b4] * (double)W_inh[(RR) * NE + e]; \
        double ic = ((RR) >= cs && (RR) < cs + 16) ? 5.0 : 0.0;          \
        0.5 * ic - 0.5 * inh;                                            \
    })
    double d0 = DRIVE(R0_), d1 = DRIVE(R1_), d2 = DRIVE(R2_);
    double d3 = DRIVE(R3_), d4 = DRIVE(R4_), d5 = DRIVE(R5_);
    double d6 = DRIVE(R6_), d7 = DRIVE(R7_), d8 = DRIVE(R8_);

    double v0 = 0, v1 = 0, v2 = 0, v3 = 0, v4 = 0, v5 = 0, v6 = 0, v7 = 0, v8 = 0;
    float  a0 = 0, a1 = 0, a2 = 0, a3 = 0, a4 = 0, a5 = 0, a6 = 0, a7 = 0, a8 = 0;

    const unsigned gOff = (unsigned)(g << 3);
    const unsigned b4B  = (unsigned)(b4 << 2);

// one slot: 4-deep pipeline, 4 entries/iter, never loads past the slot.
#define SLOT(SO, KP, RR, DD, VV, AA)                                     \
    {                                                                    \
        const char* p = wsS + (SO) + gOff;                               \
        uint2 S0 = *(const uint2*)(p);                                   \
        uint2 S1 = *(const uint2*)(p + 128);                             \
        uint2 S2 = *(const uint2*)(p + 256);                             \
        uint2 S3 = *(const uint2*)(p + 384);                             \
        double rec = 0.0;                                                \
        int k = 0;                                                       \
        while (k + 8 <= (KP)) {                                          \
            float x0 = *(const float*)(rdB + (S0.x + b4B));              \
            float x1 = *(const float*)(rdB + (S1.x + b4B));              \
            float x2 = *(const float*)(rdB + (S2.x + b4B));              \
            float x3 = *(const float*)(rdB + (S3.x + b4B));              \
            rec += (double)u2f(S0.y) * (double)x0;                       \
            rec += (double)u2f(S1.y) * (double)x1;                       \
            rec += (double)u2f(S2.y) * (double)x2;                       \
            rec += (double)u2f(S3.y) * (double)x3;                       \
            S0 = *(const uint2*)(p + 512);                               \
            S1 = *(const uint2*)(p + 640);                               \
            S2 = *(const uint2*)(p + 768);                               \
            S3 = *(const uint2*)(p + 896);                               \
            p += 512; k += 4;                                            \
        }                                                                \
        {   /* final 4 entries already in S0..S3 */                      \
            float x0 = *(const float*)(rdB + (S0.x + b4B));              \
            float x1 = *(const float*)(rdB + (S1.x + b4B));              \
            float x2 = *(const float*)(rdB + (S2.x + b4B));              \
            float x3 = *(const float*)(rdB + (S3.x + b4B));              \
            rec += (double)u2f(S0.y) * (double)x0;                       \
            rec += (double)u2f(S1.y) * (double)x1;                       \
            rec += (double)u2f(S2.y) * (double)x2;                       \
            rec += (double)u2f(S3.y) * (double)x3;                       \
        }                                                                \
        double x = (DD) + 0.3 * (((RR) < NE) ? rec : -rec);              \
        double vv = (VV);                                                \
        vv += (x - vv) * 0.5;                                            \
        double sd = (vv >= 1.0) ? 1.0 : 0.0;                             \
        vv *= (1.0 - sd);                                                \
        (VV) = vv;                                                       \
        (AA) += (float)sd;                                               \
        *(float*)(wrB + (unsigned)(RR) * ROWB + b4B) = (AA);             \
    }

    for (int tk = 0; tk < ticks; ++tk) {
        // read buf = tk&1 (tick0 reads zeroed buf0); write = the other.
        const char* rdB = accB + ((tk & 1) ? BUFB : 0u) + waveOff;
        char*       wrB = accB + ((tk & 1) ? 0u : BUFB) + waveOff;
        SLOT(SO0, KP0, R0_, d0, v0, a0);
        SLOT(SO1, KP1, R1_, d1, v1, a1);
        SLOT(SO2, KP2, R2_, d2, v2, a2);
        SLOT(SO3, KP3, R3_, d3, v3, a3);
        SLOT(SO4, KP4, R4_, d4, v4, a4);
        SLOT(SO5, KP5, R5_, d5, v5, a5);
        SLOT(SO6, KP6, R6_, d6, v6, a6);
        SLOT(SO7, KP7, R7_, d7, v7, a7);
        SLOT(SO8, KP8, R8_, d8, v8, a8);
        // no barrier: next tick reads THIS wave's own writes (program order).
    }

    if (bmine < B) {
        float* ob = out + (size_t)bmine * NE;
        if (R0_ < NE) ob[R0_] = a0;
        if (R1_ < NE) ob[R1_] = a1;
        if (R2_ < NE) ob[R2_] = a2;
        if (R3_ < NE) ob[R3_] = a3;
        if (R4_ < NE) ob[R4_] = a4;
        if (R5_ < NE) ob[R5_] = a5;
        if (R6_ < NE) ob[R6_] = a6;
        if (R7_ < NE) ob[R7_] = a7;
        if (R8_ < NE) ob[R8_] = a8;
    }
}

extern "C" void kernel_launch(void* const* d_in, const int* in_sizes, int n_in,
                              void* d_out, int out_size, void* d_ws, size_t ws_size,
                              hipStream_t stream) {
    const int*   actions = (const int*)  d_in[0];
    const float* spk     = (const float*)d_in[1];
    const float* W_rec   = (const float*)d_in[2];
    const float* W_inh   = (const float*)d_in[3];
    const int*   nt      = (const int*)  d_in[4];
    float* out = (float*)d_out;
    int B = in_sizes[0];

    int*  meta = (int*)d_ws;
    char* wsB  = (char*)d_ws;

    prep_kernel<<<1, 256, 0, stream>>>(W_rec, meta, wsB);
    int nblocks = (B + 31) / 32;
    snn_kernel<<<nblocks, THREADS, 0, stream>>>(actions, spk, W_inh, meta, wsB,
                                                nt, out, B);
}

// Round 23
// 356.420 us; speedup vs baseline: 3.0412x; 1.5361x over previous
//
#include <hip/hip_runtime.h>
#include <string.h>

// TopographicIntentMap FINAL (= R15, 353.9us best): R7 skeleton + nnz-balanced
// snake deal. Session evidence (R3-R22):
//  - fp64 pipeline required: checker ref is np-fp64 recompute (R3).
//  - lane=batch + wave-uniform CSR rows -> conflict-free gathers (R4: 879->470).
//  - CSR stream on vector-VMEM path (vz trick), mov-free depth-2 pipeline
//    (R6/R7: 470->362).
//  - nnz-sorted snake deal equalizes per-wave work -> less barrier convoy
//    (R15: 362->354).
// Falsified levers (kept out): dual-acc ILP (R16 neutral), f64-weight stream
// (R17: L1 blowout), pad x2 (R18 neutral), quad-row b128 (R13: FETCH blowup),
// 2-blocks/CU (R14: occupancy loss), barrier-free drift (R19-R22: spills,
// then inherent bank conflicts; best 547).
// Remaining wall: VALU 62% + DS ~50% alternating around the per-tick barrier;
// every attempt to overlap them hit a structural hazard. Practical floor.

#define NN 144
#define NE 115
#define NB 64            // batches per block (= lanes)
#define SLOTS 9          // rows per wave: 16*9 = 144
#define THREADS 1024

#define STREAM_BASE 4096 // stream region in ws (bytes); meta at ws[0..2KB)
#define META_STRIDE 32   // ints per wave: [0]=base entry idx, [1+r]=row, [10+r]=kp

__device__ __forceinline__ float u2f(unsigned u) {
    float f; memcpy(&f, &u, 4); return f;
}

__global__ void prep_kernel(const float* __restrict__ W_rec,
                            int* __restrict__ meta, char* __restrict__ wsB) {
    __shared__ int cnt[NN], sorted[NN], rowOff[NN];
    const int t = threadIdx.x;

    // zero stream region (pads + prefetch-overrun tail): 48KB
    for (int i = t; i < 49152 / 4; i += 256) ((int*)(wsB + STREAM_BASE))[i] = 0;

    if (t < NN) {
        int c = 0;
        for (int j = 0; j < NN; ++j) c += (W_rec[t * NN + j] != 0.0f);
        cnt[t] = c;
    }
    __syncthreads();
    if (t < NN) {   // deterministic descending rank (ties by index)
        int ct = cnt[t], r = 0;
        for (int j = 0; j < NN; ++j) {
            int cj = cnt[j];
            r += (cj > ct) || (cj == ct && j < t);
        }
        sorted[r] = t;
    }
    __syncthreads();
    if (t == 0) {
        int off = 0;
        for (int w = 0; w < 16; ++w) {
            int* m = meta + w * META_STRIDE;
            m[0] = off;                          // wave base entry index
            for (int r = 0; r < SLOTS; ++r) {
                int pos = (r & 1) ? (15 - w) : w;        // snake deal
                int row = sorted[r * 16 + pos];
                int c = cnt[row];
                int kp = ((c < 1 ? 1 : c) + 3) & ~3;     // pad to x4, min 4
                m[1 + r]  = row;
                m[10 + r] = kp;
                rowOff[row] = off;
                off += kp;
            }
        }
    }
    __syncthreads();
    if (t < NN) {            // fill each row's entries at its offset
        char* base = wsB + STREAM_BASE + (size_t)rowOff[t] * 8;
        int k = 0;
        for (int j = 0; j < NN; ++j) {
            float w = W_rec[t * NN + j];
            if (w != 0.0f) {
                *(unsigned*)(base + (size_t)k * 8)     = (unsigned)j * 256u;
                *(float*)(base + (size_t)k * 8 + 4)    = w;
                ++k;
            }
        }
        // (pads already zeroed; zero pads are exact +0.0*acc[0] no-ops)
    }
}

// 4 entries from two uint4 regs: {colByte,w} pairs; k-ascending f64 FMA.
#define GFMA4(S0, S1)                                                   \
    {                                                                   \
        float a0 = *(const float*)(ldsB + ((S0).x + lro));              \
        float a1 = *(const float*)(ldsB + ((S0).z + lro));              \
        float a2 = *(const float*)(ldsB + ((S1).x + lro));              \
        float a3 = *(const float*)(ldsB + ((S1).z + lro));              \
        rec += (double)u2f((S0).y) * (double)a0;                        \
        rec += (double)u2f((S0).w) * (double)a1;                        \
        rec += (double)u2f((S1).y) * (double)a2;                        \
        rec += (double)u2f((S1).w) * (double)a3;                        \
    }

__global__ __launch_bounds__(THREADS) void snn_kernel(
        const int*   __restrict__ actions,
        const float* __restrict__ spk,      // [B,8,115]
        const float* __restrict__ W_inh,    // [144,115]
        const int*   __restrict__ meta,
        const uint4* __restrict__ csrQ,     // stream: 2 entries per uint4
        const int*   __restrict__ nt_ptr,
        float*       __restrict__ out,      // [B,115]
        int B) {
    __shared__ float accF[2][NN * NB];      // 73728 B, double-buffered
    __shared__ int   metaL[16 * META_STRIDE];

    const char* ldsB = (const char*)&accF[0][0];
    float* nbF = &accF[1][0];               // [NE][65] alias, pre-loop only

    const int t    = threadIdx.x;
    const int lane = t & 63;
    const int wid  = t >> 6;
    const int b0   = blockIdx.x * NB;
    const int b    = b0 + lane;
    const int ticks = *nt_ptr;

    // opaque per-lane zero: keeps the CSR stream on the vector VMEM path
    int vz;
    asm volatile("v_mov_b32 %0, 0" : "=v"(vz));

    if (t < 16 * META_STRIDE) metaL[t] = meta[t];

    // stage neighbor sums into nbF[e][bb]
    for (int p = t; p < NB * NE; p += THREADS) {
        int bb = p / NE;
        int e  = p - bb * NE;
        float s = 0.0f;
        if (b0 + bb < B) {
            const float* sp = spk + ((size_t)(b0 + bb) * 8) * NE + e;
            #pragma unroll
            for (int n = 0; n < 8; ++n) s += sp[n * NE];
        }
        nbF[e * (NB + 1) + bb] = s;
    }
    for (int i = t; i < NN * NB; i += THREADS) accF[0][i] = 0.0f;
    __syncthreads();

    // wave-uniform metadata (SGPRs)
    const int mb = wid * META_STRIDE;
    const int sbase = __builtin_amdgcn_readfirstlane(metaL[mb]);
    int rows[SLOTS], skp[SLOTS];
    #pragma unroll
    for (int r = 0; r < SLOTS; ++r) {
        rows[r] = __builtin_amdgcn_readfirstlane(metaL[mb + 1 + r]);
        skp[r]  = __builtin_amdgcn_readfirstlane(metaL[mb + 10 + r]);
    }

    // per-row drives (fp64, e ascending — same association as R4-R22)
    double drv[SLOTS];
    {
        int a = (b < B) ? actions[b] : 4;
        int cs = ((a == 0) ? 5 : (a == 1) ? 1 : (a == 2) ? 3 : (a == 3) ? 7 : 4) * 16;
        #pragma unroll
        for (int r = 0; r < SLOTS; ++r) {
            double inh = 0.0;
            for (int e = 0; e < NE; ++e)
                inh += (double)nbF[e * (NB + 1) + lane]
                     * (double)W_inh[rows[r] * NE + e];
            double ic = (rows[r] >= cs && rows[r] < cs + 16) ? 5.0 : 0.0;
            drv[r] = 0.5 * ic - 0.5 * inh;
        }
    }

    const uint4* pBase = csrQ + (sbase >> 1) + vz;   // per-lane ptr (VMEM)

    double v[SLOTS];
    float  accv[SLOTS];
    #pragma unroll
    for (int r = 0; r < SLOTS; ++r) { v[r] = 0.0; accv[r] = 0.0f; }

    for (int tk = 0; tk < ticks; ++tk) {
        __syncthreads();   // prev tick's acc writes (or initial zeros) visible
        const unsigned rbOff = (tk & 1) ? 36864u : 0u;
        const unsigned lro   = (unsigned)(lane * 4) + rbOff;
        char* WbB = (char*)ldsB + ((tk & 1) ? 0u : 36864u);

        // prime: SA = entries 0..3, SB = 4..7 of this wave's flat stream
        const uint4* p = pBase;
        uint4 SA0 = p[0], SA1 = p[1];
        uint4 SB0 = p[2], SB1 = p[3];

        #pragma unroll
        for (int r = 0; r < SLOTS; ++r) {
            double rec = 0.0;
            int k = 0;
            const int kend = skp[r];
            // steady state: 2 chunks (8 entries)/iter, zero rotation movs
            while (k + 8 <= kend) {
                GFMA4(SA0, SA1);
                SA0 = p[4]; SA1 = p[5];
                GFMA4(SB0, SB1);
                SB0 = p[6]; SB1 = p[7];
                p += 4; k += 8;
            }
            if (k < kend) {                  // kend%8==4 leftover chunk
                GFMA4(SA0, SA1);
                SA0 = SB0; SA1 = SB1;
                SB0 = p[4]; SB1 = p[5];
                p += 2;
            }
            // invariant: SA = next slot's first chunk, SB = second
            const int o = rows[r];
            double x = drv[r] + 0.3 * ((o < NE) ? rec : -rec);
            double vv = v[r];
            vv += (x - vv) * 0.5;
            double sd = (vv >= 1.0) ? 1.0 : 0.0;
            vv *= (1.0 - sd);
            v[r] = vv;
            accv[r] += (float)sd;
            *(float*)(WbB + ((unsigned)o << 8) + lane * 4) = accv[r];
        }
    }

    if (b < B) {
        #pragma unroll
        for (int r = 0; r < SLOTS; ++r) {
            int o = rows[r];
            if (o < NE) out[(size_t)b * NE + o] = accv[r];
        }
    }
}

extern "C" void kernel_launch(void* const* d_in, const int* in_sizes, int n_in,
                              void* d_out, int out_size, void* d_ws, size_t ws_size,
                              hipStream_t stream) {
    const int*   actions = (const int*)  d_in[0];
    const float* spk     = (const float*)d_in[1];
    const float* W_rec   = (const float*)d_in[2];
    const float* W_inh   = (const float*)d_in[3];
    const int*   nt      = (const int*)  d_in[4];
    float* out = (float*)d_out;
    int B = in_sizes[0];

    int*  meta = (int*)d_ws;
    char* wsB  = (char*)d_ws;
    const uint4* csrQ = (const uint4*)(wsB + STREAM_BASE);

    prep_kernel<<<1, 256, 0, stream>>>(W_rec, meta, wsB);
    int nblocks = (B + NB - 1) / NB;
    snn_kernel<<<nblocks, THREADS, 0, stream>>>(actions, spk, W_inh, meta, csrQ,
                                                nt, out, B);
}